// Round 3
// baseline (254.135 us; speedup 1.0000x reference)
//
#include <hip/hip_runtime.h>
#include <math.h>

// SpecNorm: x[B,T,F,2] fp32 -> x * rsqrt(ema(|x|) + eps)
// EMA sequential in T; lookback reconstructs state (0.9^64 ~= 1.2e-3 rel
// error in s -> ~7e-3 extra output error; threshold 0.129, measured base
// absmax 0.0156).
//
// R7: R6 crashed -- geometry bug: OUT0=47 < LOOKBACK=64 made chunk 1's
// warmup start at t = 47-64 = -17 (reads before the buffer; fault at b=0).
// Constraint: OUT0 >= LOOKBACK. Fixed geometry OUT0=110, OUTN=30
// (110 + 63*30 = 2000; chunk 1 tstart = 46). Batch counts 13/3 (both odd),
// remainder 6 for both -> same prefetched-remainder epilogue.
//
// Carried from R6 (R5 post-mortem): 7277 cyc per 8-row batch == 8 serialized
// ~900 cyc HBM round-trips -- the CP8 copy chain forced re-serialization
// (VGPR=40 => single buffer), MLP ~1, and 1024 waves ~= 1 MB in flight
// < 2.4 MB Little's-law need. Fixes:
//  (a) copy-free ping-pong (LD8(b);OUT8(a);LD8(a);OUT8(b)) -- no copies, no
//      phis over load data; remainder (6 rows) prefetched into the idle
//      buffer before the last batch's stores => no serial tail.
//  (b) 4x TLP: LOOKBACK 64, NCH 64 => 1024 blocks, 4/CU, 16 waves/CU.

#define ALPHA 0.9f
#define OMA   0.1f
#define EPS_  1e-12f

// aligned(8): row base float-index is (b*2000+t)*962 == 2t mod 4, so odd
// rows give only 8 B alignment for the per-thread quad.
typedef float vf4 __attribute__((ext_vector_type(4), aligned(8)));
typedef float vf2 __attribute__((ext_vector_type(2), aligned(8)));

constexpr int B_ = 16, T_ = 2000, F_ = 481;
constexpr int NCH = 64, LOOKBACK = 64;
constexpr int OUT0 = 110, OUTN = 30;    // 110 + 63*30 = 2000; both %8 == 6
constexpr int ROWF = 2 * F_;            // 962 floats per row

// 8 independent dwordx4 loads issued back-to-back (MLP 8), then advance.
#define LD8(V) do { \
  V##0 = *(const vf4*)(xp + 0 * ROWF); \
  V##1 = *(const vf4*)(xp + 1 * ROWF); \
  V##2 = *(const vf4*)(xp + 2 * ROWF); \
  V##3 = *(const vf4*)(xp + 3 * ROWF); \
  V##4 = *(const vf4*)(xp + 4 * ROWF); \
  V##5 = *(const vf4*)(xp + 5 * ROWF); \
  V##6 = *(const vf4*)(xp + 6 * ROWF); \
  V##7 = *(const vf4*)(xp + 7 * ROWF); \
  xp += 8 * ROWF; \
} while (0)

// 6 remainder loads (no advance needed afterwards).
#define LD6(V) do { \
  V##0 = *(const vf4*)(xp + 0 * ROWF); \
  V##1 = *(const vf4*)(xp + 1 * ROWF); \
  V##2 = *(const vf4*)(xp + 2 * ROWF); \
  V##3 = *(const vf4*)(xp + 3 * ROWF); \
  V##4 = *(const vf4*)(xp + 4 * ROWF); \
  V##5 = *(const vf4*)(xp + 5 * ROWF); \
} while (0)

#define EMA1(v) do { \
  float aA = __builtin_amdgcn_sqrtf((v).x * (v).x + (v).y * (v).y); \
  float aB = __builtin_amdgcn_sqrtf((v).z * (v).z + (v).w * (v).w); \
  sA = ALPHA * sA + OMA * aA; \
  sB = ALPHA * sB + OMA * aB; \
} while (0)

#define EMA8(V) do { EMA1(V##0); EMA1(V##1); EMA1(V##2); EMA1(V##3); \
                     EMA1(V##4); EMA1(V##5); EMA1(V##6); EMA1(V##7); } while (0)

// One output row: EMA update, rsqrt, single contiguous 16 B nt store per lane
// (tid==240 stores only its valid 8 B A-half; a 16 B store there would
// clobber the next row's f=0, owned by tid 0 of this block).
#define OUT1(v) do { \
  EMA1(v); \
  float iA = __builtin_amdgcn_rsqf(sA + EPS_); \
  float iB = __builtin_amdgcn_rsqf(sB + EPS_); \
  if (hasB) { \
    vf4 o = { (v).x * iA, (v).y * iA, (v).z * iB, (v).w * iB }; \
    __builtin_nontemporal_store(o, (vf4*)op); \
  } else { \
    vf2 o = { (v).x * iA, (v).y * iA }; \
    __builtin_nontemporal_store(o, (vf2*)op); \
  } \
  op += ROWF; \
} while (0)

#define OUT8(V) do { OUT1(V##0); OUT1(V##1); OUT1(V##2); OUT1(V##3); \
                     OUT1(V##4); OUT1(V##5); OUT1(V##6); OUT1(V##7); } while (0)

#define OUT6(V) do { OUT1(V##0); OUT1(V##1); OUT1(V##2); OUT1(V##3); \
                     OUT1(V##4); OUT1(V##5); } while (0)

__global__ __launch_bounds__(256, 1)
void specnorm_kernel(const float* __restrict__ x, float* __restrict__ out,
                     float* __restrict__ ws) {
    const int tid = threadIdx.x;
    if (tid > 240) return;              // 241..255 idle (6% waste)
    const int chunk = blockIdx.x;
    const int b = blockIdx.y;
    const bool hasB = (tid < 240);      // tid==240 owns only f=480

    // s0[f] = 0.001 + f*step
    const float step = (float)((0.0001 - 0.001) / (double)(F_ - 1));
    float sA = 0.001f + (float)(2 * tid) * step;
    float sB = 0.001f + (float)(2 * tid + 1) * step;

    const int tout0 = (chunk == 0) ? 0 : OUT0 + (chunk - 1) * OUTN;
    const int nb    = (chunk == 0) ? (OUT0 / 8) : (OUTN / 8);  // 13 or 3 (odd)
    const int nwarm = (chunk == 0) ? 0 : LOOKBACK;
    const int tstart = tout0 - nwarm;   // >= 46 for chunk >= 1 (OUT0>=LOOKBACK)

    // NOTE: tid==240's 16 B load reads 8 B past the row (= next row's f=0,
    // harmless). At the very last row of the buffer this over-reads 8 B past
    // the end; allocation is page-granular with ~2 KB slack (123,136,000 B
    // is not page-multiple), so the access stays mapped.
    const float* xp = x + (size_t)(b * T_ + tstart) * ROWF + 4 * tid;
    float* op = out + (size_t)(b * T_ + tout0) * ROWF + 4 * tid;
    (void)ws;

    vf4 a0, a1, a2, a3, a4, a5, a6, a7;
    vf4 b0, b1, b2, b3, b4, b5, b6, b7;

    // ---- warmup: EMA only, no stores. 64 rows = 8 batches (even). ----
    // Copy-free ping-pong; EMA batches processed strictly in order.
    if (nwarm) {
        LD8(a);
        #pragma unroll
        for (int i = 0; i < 3; ++i) {
            LD8(b); EMA8(a);            // loads batch 2i+1; consumes 2i
            LD8(a); EMA8(b);            // loads batch 2i+2; consumes 2i+1
        }
        LD8(b); EMA8(a); EMA8(b);       // batches 6, 7
    }

    // ---- main: nb odd (13 or 3) full batches + fixed 6-row remainder ----
    LD8(a);
    for (int i = 1; i + 1 < nb; i += 2) {
        LD8(b); OUT8(a);
        LD8(a); OUT8(b);
    }
    LD6(b);                 // remainder loads in flight during last batch
    OUT8(a);
    OUT6(b);
}

extern "C" void kernel_launch(void* const* d_in, const int* in_sizes, int n_in,
                              void* d_out, int out_size, void* d_ws, size_t ws_size,
                              hipStream_t stream) {
    const float* x = (const float*)d_in[0];
    float* out = (float*)d_out;
    float* ws = (float*)d_ws;

    dim3 grid(NCH, B_);          // 1024 blocks x 4 waves = 4096 waves, 4 blk/CU
    dim3 block(256);
    specnorm_kernel<<<grid, block, 0, stream>>>(x, out, ws);
}

// Round 4
// 248.916 us; speedup vs baseline: 1.0210x; 1.0210x over previous
//
#include <hip/hip_runtime.h>
#include <math.h>

// SpecNorm: x[B,T,F,2] fp32 -> x * rsqrt(ema(|x|) + eps)
// EMA sequential in T; lookback reconstructs state (0.9^64 ~= 1.2e-3 rel
// error in s; threshold 0.129, measured absmax 0.031).
//
// R8: R7 post-mortem -- VGPR=40 proved the scheduler sank each load to just
// before its use (min-RP), which (a) killed MLP and (b) put every load
// YOUNGER than the previous row's nt stores in the vmem FIFO, so each
// load-wait drained store acks from HBM (~2900 cyc/row measured == store-ack
// + load latency). Fixes:
//  (a) __builtin_amdgcn_sched_barrier(0) fences between every LD/OUT/EMA
//      phase: loads issue 8-back-to-back, OLDER than the following stores,
//      and stay live across the fence (forces true 2-buffer ping-pong;
//      waits become counted vmcnt, store acks never drained in-loop).
//  (b) XCD-bijective chunk swizzle (64 chunks = 8 groups x 8 XCDs): chunk
//      c and c+1 share an XCD so c+1's warmup reads (= c's read tail) hit
//      L2 (R7 FETCH 183 MB vs 118 MB input: ~half the warmup missed L2).
// Geometry: OUT0=110 >= LOOKBACK=64 (R6 fault), OUTN=30; 110+63*30=2000;
// batch counts 13/3 (both odd), remainder 6 -> one prefetched epilogue.

#define ALPHA 0.9f
#define OMA   0.1f
#define EPS_  1e-12f

// aligned(8): row base float-index is (b*2000+t)*962 == 2t mod 4, so odd
// rows give only 8 B alignment for the per-thread quad.
typedef float vf4 __attribute__((ext_vector_type(4), aligned(8)));
typedef float vf2 __attribute__((ext_vector_type(2), aligned(8)));

constexpr int B_ = 16, T_ = 2000, F_ = 481;
constexpr int NCH = 64, LOOKBACK = 64;
constexpr int OUT0 = 110, OUTN = 30;    // 110 + 63*30 = 2000; both %8 == 6
constexpr int ROWF = 2 * F_;            // 962 floats per row

#define SB() __builtin_amdgcn_sched_barrier(0)

// 8 independent dwordx4 loads issued back-to-back (MLP 8), then advance.
#define LD8(V) do { \
  V##0 = *(const vf4*)(xp + 0 * ROWF); \
  V##1 = *(const vf4*)(xp + 1 * ROWF); \
  V##2 = *(const vf4*)(xp + 2 * ROWF); \
  V##3 = *(const vf4*)(xp + 3 * ROWF); \
  V##4 = *(const vf4*)(xp + 4 * ROWF); \
  V##5 = *(const vf4*)(xp + 5 * ROWF); \
  V##6 = *(const vf4*)(xp + 6 * ROWF); \
  V##7 = *(const vf4*)(xp + 7 * ROWF); \
  xp += 8 * ROWF; \
} while (0)

// 6 remainder loads (no advance needed afterwards).
#define LD6(V) do { \
  V##0 = *(const vf4*)(xp + 0 * ROWF); \
  V##1 = *(const vf4*)(xp + 1 * ROWF); \
  V##2 = *(const vf4*)(xp + 2 * ROWF); \
  V##3 = *(const vf4*)(xp + 3 * ROWF); \
  V##4 = *(const vf4*)(xp + 4 * ROWF); \
  V##5 = *(const vf4*)(xp + 5 * ROWF); \
} while (0)

#define EMA1(v) do { \
  float aA = __builtin_amdgcn_sqrtf((v).x * (v).x + (v).y * (v).y); \
  float aB = __builtin_amdgcn_sqrtf((v).z * (v).z + (v).w * (v).w); \
  sA = ALPHA * sA + OMA * aA; \
  sB = ALPHA * sB + OMA * aB; \
} while (0)

#define EMA8(V) do { EMA1(V##0); EMA1(V##1); EMA1(V##2); EMA1(V##3); \
                     EMA1(V##4); EMA1(V##5); EMA1(V##6); EMA1(V##7); } while (0)

// One output row: EMA update, rsqrt, single contiguous 16 B nt store per lane
// (tid==240 stores only its valid 8 B A-half; a 16 B store there would
// clobber the next row's f=0, owned by tid 0 of this block).
#define OUT1(v) do { \
  EMA1(v); \
  float iA = __builtin_amdgcn_rsqf(sA + EPS_); \
  float iB = __builtin_amdgcn_rsqf(sB + EPS_); \
  if (hasB) { \
    vf4 o = { (v).x * iA, (v).y * iA, (v).z * iB, (v).w * iB }; \
    __builtin_nontemporal_store(o, (vf4*)op); \
  } else { \
    vf2 o = { (v).x * iA, (v).y * iA }; \
    __builtin_nontemporal_store(o, (vf2*)op); \
  } \
  op += ROWF; \
} while (0)

#define OUT8(V) do { OUT1(V##0); OUT1(V##1); OUT1(V##2); OUT1(V##3); \
                     OUT1(V##4); OUT1(V##5); OUT1(V##6); OUT1(V##7); } while (0)

#define OUT6(V) do { OUT1(V##0); OUT1(V##1); OUT1(V##2); OUT1(V##3); \
                     OUT1(V##4); OUT1(V##5); } while (0)

__global__ __launch_bounds__(256, 1)
void specnorm_kernel(const float* __restrict__ x, float* __restrict__ out,
                     float* __restrict__ ws) {
    const int tid = threadIdx.x;
    if (tid > 240) return;              // 241..255 idle (6% waste)
    // XCD-bijective swizzle: 64 chunks, 8 XCDs (round-robin on linear block
    // id => XCD = bx % 8). chunk = (bx%8)*8 + bx/8 puts chunks 8k..8k+7 on
    // XCD k, so chunk c+1's warmup span (chunk c's read tail) is L2-local.
    const int bx = blockIdx.x;
    const int chunk = ((bx & 7) << 3) | (bx >> 3);
    const int b = blockIdx.y;
    const bool hasB = (tid < 240);      // tid==240 owns only f=480

    // s0[f] = 0.001 + f*step
    const float step = (float)((0.0001 - 0.001) / (double)(F_ - 1));
    float sA = 0.001f + (float)(2 * tid) * step;
    float sB = 0.001f + (float)(2 * tid + 1) * step;

    const int tout0 = (chunk == 0) ? 0 : OUT0 + (chunk - 1) * OUTN;
    const int nb    = (chunk == 0) ? (OUT0 / 8) : (OUTN / 8);  // 13 or 3 (odd)
    const int nwarm = (chunk == 0) ? 0 : LOOKBACK;
    const int tstart = tout0 - nwarm;   // >= 46 for chunk >= 1 (OUT0>=LOOKBACK)

    // NOTE: tid==240's 16 B load reads 8 B past the row (= next row's f=0,
    // harmless). At the very last row of the buffer this over-reads 8 B past
    // the end; allocation is page-granular with ~2 KB slack (123,136,000 B
    // is not page-multiple), so the access stays mapped.
    const float* xp = x + (size_t)(b * T_ + tstart) * ROWF + 4 * tid;
    float* op = out + (size_t)(b * T_ + tout0) * ROWF + 4 * tid;
    (void)ws;

    vf4 a0, a1, a2, a3, a4, a5, a6, a7;
    vf4 b0, b1, b2, b3, b4, b5, b6, b7;

    // ---- warmup: EMA only, no stores. 64 rows = 8 batches (even). ----
    if (nwarm) {
        LD8(a); SB();
        #pragma unroll
        for (int i = 0; i < 3; ++i) {
            LD8(b); SB(); EMA8(a); SB();   // loads 2i+1 in flight over EMA 2i
            LD8(a); SB(); EMA8(b); SB();   // loads 2i+2 in flight over 2i+1
        }
        LD8(b); SB(); EMA8(a); SB(); EMA8(b); SB();
    }

    // ---- main: nb odd (13 or 3) full batches + fixed 6-row remainder ----
    // Loads always issue BEFORE the batch of stores that follows them in the
    // vmem FIFO => load-waits are counted vmcnt, never drain nt-store acks.
    LD8(a); SB();
    for (int i = 1; i + 1 < nb; i += 2) {
        LD8(b); SB(); OUT8(a); SB();
        LD8(a); SB(); OUT8(b); SB();
    }
    LD6(b); SB();           // remainder loads in flight during last batch
    OUT8(a); SB();
    OUT6(b);
}

extern "C" void kernel_launch(void* const* d_in, const int* in_sizes, int n_in,
                              void* d_out, int out_size, void* d_ws, size_t ws_size,
                              hipStream_t stream) {
    const float* x = (const float*)d_in[0];
    float* out = (float*)d_out;
    float* ws = (float*)d_ws;

    dim3 grid(NCH, B_);          // 1024 blocks x 4 waves = 4096 waves, 4 blk/CU
    dim3 block(256);
    specnorm_kernel<<<grid, block, 0, stream>>>(x, out, ws);
}

// Round 5
// 248.136 us; speedup vs baseline: 1.0242x; 1.0031x over previous
//
#include <hip/hip_runtime.h>
#include <math.h>

// SpecNorm: x[B,T,F,2] fp32 -> x * rsqrt(ema(|x|) + eps)
// EMA sequential in T; lookback reconstructs state (0.9^64 ~= 1.2e-3 rel
// error in s; threshold 0.129, measured absmax 0.031).
//
// R9: R8 post-mortem -- VGPR=40 again: sched_barrier(0) did NOT stop the
// backend from sinking loads to uses (single-buffer allocation, ~21,400
// cyc/batch == store-ack+load serial signature, waves have a load in
// flight only ~4% of the time). Swizzle lever verified separately
// (FETCH 183->158 MB). R7/R8 prove hipcc defeats any source-level
// pipeline, so this round moves the loads to inline asm:
//  - global_load_dwordx4 via asm volatile ("=&v" outs): un-sinkable,
//    outputs forced live across the consuming phase => real 2-buffer
//    ping-pong, 8 loads in flight per wave at high duty cycle.
//  - hand-counted s_waitcnt vmcnt(N) (+sched_barrier(0), rule #18):
//    steady state ALD8;W16;OUT8 -- the wait retires exactly the
//    2-phase-old stores + the batch we need; never drains young store
//    acks; never vmcnt(0) in-loop. FIFO walked for nb=13/nb=3 + rem6
//    epilogue (W16/W14/W8); warmup chains into main with no drain (b0
//    prefetched under the final warmup EMA).
// Geometry (R6 fault): OUT0=110 >= LOOKBACK=64, OUTN=30; 110+63*30=2000;
// nb = 13 or 3 (odd), remainder 6. XCD-bijective chunk swizzle kept.

#define ALPHA 0.9f
#define OMA   0.1f
#define EPS_  1e-12f

// aligned(8): row base float-index is (b*2000+t)*962 == 2t mod 4, so odd
// rows give only 8 B alignment for the per-thread quad.
typedef float vf4 __attribute__((ext_vector_type(4), aligned(8)));
typedef float vf2 __attribute__((ext_vector_type(2), aligned(8)));

constexpr int B_ = 16, T_ = 2000, F_ = 481;
constexpr int NCH = 64, LOOKBACK = 64;
constexpr int OUT0 = 110, OUTN = 30;    // 110 + 63*30 = 2000; both %8 == 6
constexpr int ROWF = 2 * F_;            // 962 floats per row (3848 B)

#define SB() __builtin_amdgcn_sched_barrier(0)
// Counted wait: N youngest vmem ops may remain outstanding. sched_barrier
// right after so dependent VALU can't be hoisted past it (rule #18).
#define WAITV(N) do { \
  asm volatile("s_waitcnt vmcnt(" #N ")" ::: "memory"); SB(); \
} while (0)

// Two rows from one pointer: offset imm is 13-bit signed, row stride
// 3848 B fits once. "=&v" earlyclobber: dest must not alias the addr pair.
#define ALD2(d0, d1, p) \
  asm volatile("global_load_dwordx4 %0, %2, off\n\t" \
               "global_load_dwordx4 %1, %2, off offset:3848" \
               : "=&v"(d0), "=&v"(d1) : "v"(p))

// 8-row batch: 8 loads issued back-to-back (MLP 8), pointers advance 8 rows.
#define ALD8(V) do { \
  ALD2(V##0, V##1, p0); ALD2(V##2, V##3, p1); \
  ALD2(V##4, V##5, p2); ALD2(V##6, V##7, p3); \
  p0 += 8 * ROWF; p1 += 8 * ROWF; p2 += 8 * ROWF; p3 += 8 * ROWF; \
} while (0)

// 6-row remainder (no advance afterwards).
#define ALD6(V) do { \
  ALD2(V##0, V##1, p0); ALD2(V##2, V##3, p1); \
  ALD2(V##4, V##5, p2); \
} while (0)

#define EMA1(v) do { \
  float aA = __builtin_amdgcn_sqrtf((v).x * (v).x + (v).y * (v).y); \
  float aB = __builtin_amdgcn_sqrtf((v).z * (v).z + (v).w * (v).w); \
  sA = ALPHA * sA + OMA * aA; \
  sB = ALPHA * sB + OMA * aB; \
} while (0)

#define EMA8(V) do { EMA1(V##0); EMA1(V##1); EMA1(V##2); EMA1(V##3); \
                     EMA1(V##4); EMA1(V##5); EMA1(V##6); EMA1(V##7); } while (0)

// One output row: EMA update, rsqrt, single contiguous 16 B nt store per lane
// (tid==240 stores only its valid 8 B A-half; a 16 B store there would
// clobber the next row's f=0, owned by tid 0 of this block).
#define OUT1(v) do { \
  EMA1(v); \
  float iA = __builtin_amdgcn_rsqf(sA + EPS_); \
  float iB = __builtin_amdgcn_rsqf(sB + EPS_); \
  if (hasB) { \
    vf4 o = { (v).x * iA, (v).y * iA, (v).z * iB, (v).w * iB }; \
    __builtin_nontemporal_store(o, (vf4*)op); \
  } else { \
    vf2 o = { (v).x * iA, (v).y * iA }; \
    __builtin_nontemporal_store(o, (vf2*)op); \
  } \
  op += ROWF; \
} while (0)

#define OUT8(V) do { OUT1(V##0); OUT1(V##1); OUT1(V##2); OUT1(V##3); \
                     OUT1(V##4); OUT1(V##5); OUT1(V##6); OUT1(V##7); } while (0)

#define OUT6(V) do { OUT1(V##0); OUT1(V##1); OUT1(V##2); OUT1(V##3); \
                     OUT1(V##4); OUT1(V##5); } while (0)

__global__ __launch_bounds__(256, 1)
void specnorm_kernel(const float* __restrict__ x, float* __restrict__ out,
                     float* __restrict__ ws) {
    const int tid = threadIdx.x;
    if (tid > 240) return;              // 241..255 idle (6% waste)
    // XCD-bijective swizzle: 64 chunks = 8 groups x 8 XCDs; chunks 8k..8k+7
    // share XCD k so chunk c+1's warmup span (= chunk c's read tail) is
    // L2-local. Verified in R8: FETCH 183 -> 158 MB.
    const int bx = blockIdx.x;
    const int chunk = ((bx & 7) << 3) | (bx >> 3);
    const int b = blockIdx.y;
    const bool hasB = (tid < 240);      // tid==240 owns only f=480

    // s0[f] = 0.001 + f*step
    const float step = (float)((0.0001 - 0.001) / (double)(F_ - 1));
    float sA = 0.001f + (float)(2 * tid) * step;
    float sB = 0.001f + (float)(2 * tid + 1) * step;

    const int tout0 = (chunk == 0) ? 0 : OUT0 + (chunk - 1) * OUTN;
    const int nb    = (chunk == 0) ? (OUT0 / 8) : (OUTN / 8);  // 13 or 3 (odd)
    const int nwarm = (chunk == 0) ? 0 : LOOKBACK;
    const int tstart = tout0 - nwarm;   // >= 46 for chunk >= 1 (OUT0>=LOOKBACK)

    // NOTE: tid==240's 16 B load reads 8 B past the row (= next row's f=0,
    // harmless). At the very last row of the buffer this over-reads 8 B past
    // the end; allocation is page-granular with ~2 KB slack (123,136,000 B
    // is not page-multiple), so the access stays mapped.
    const float* base = x + (size_t)(b * T_ + tstart) * ROWF + 4 * tid;
    const float* p0 = base;
    const float* p1 = base + 2 * ROWF;
    const float* p2 = base + 4 * ROWF;
    const float* p3 = base + 6 * ROWF;
    float* op = out + (size_t)(b * T_ + tout0) * ROWF + 4 * tid;
    (void)ws;

    vf4 a0, a1, a2, a3, a4, a5, a6, a7;
    vf4 b0, b1, b2, b3, b4, b5, b6, b7;

    // ---- warmup: EMA only, no stores. 64 rows = 8 batches w0..w7. ----
    // Each WAITV(8) fires with exactly two load-batches outstanding and
    // retires the older one. The final ALD8(a) prefetches main's batch 0
    // under the last warmup EMA -- no drain at the boundary.
    if (nwarm) {
        ALD8(a);                            // w0
        #pragma unroll
        for (int i = 0; i < 3; ++i) {
            ALD8(b); WAITV(8); EMA8(a);     // w(2i+1) in flight over w(2i)
            ALD8(a); WAITV(8); EMA8(b);     // w(2i+2) in flight over w(2i+1)
        }
        ALD8(b); WAITV(8); EMA8(a);         // w7 issued, w6 consumed
        ALD8(a); WAITV(8); EMA8(b);         // batch 0 issued!, w7 consumed
    } else {
        ALD8(a);                            // batch 0
    }

    // ---- main: nb odd full batches + 6-row remainder. FIFO walk:
    // steady state entering loop body: [S(k-1):8, L(k+1):8] outstanding.
    // W16 always retires {2-phase-old stores, the load batch we need}.
    ALD8(b); WAITV(8); OUT8(a);             // batch 1 in, out batch 0
    const int m = nb / 2;                   // 6 or 1
    for (int i = 0; i < m - 1; ++i) {
        ALD8(a); WAITV(16); OUT8(b);        // out b(2i+1)
        ALD8(b); WAITV(16); OUT8(a);        // out b(2i+2)
    }
    ALD8(a); WAITV(16); OUT8(b);            // out b(nb-2)
    ALD6(b); WAITV(14); OUT8(a);            // rem in flight, out b(nb-1)
    WAITV(8); OUT6(b);                      // rem (stores of b(nb-1) stay out)
}

extern "C" void kernel_launch(void* const* d_in, const int* in_sizes, int n_in,
                              void* d_out, int out_size, void* d_ws, size_t ws_size,
                              hipStream_t stream) {
    const float* x = (const float*)d_in[0];
    float* out = (float*)d_out;
    float* ws = (float*)d_ws;

    dim3 grid(NCH, B_);          // 1024 blocks x 4 waves = 4096 waves, 4 blk/CU
    dim3 block(256);
    specnorm_kernel<<<grid, block, 0, stream>>>(x, out, ws);
}

// Round 6
// 240.625 us; speedup vs baseline: 1.0561x; 1.0312x over previous
//
#include <hip/hip_runtime.h>
#include <math.h>

// SpecNorm: x[B,T,F,2] fp32 -> x * rsqrt(ema(|x|) + eps)
// EMA sequential in T; lookback reconstructs state (0.9^128 ~= 1.4e-6 rel
// error; threshold 0.129, measured absmax 0.0156 at LOOKBACK=128).
//
// R10: R9 post-mortem -- dur invariant across R7/R8/R9 (and R5's 94 us at
// 16x less concurrency): the kernel is HBM-throughput-saturated at
// ~2.7 TB/s; waits are backpressure, not latency. Remaining levers:
//  (a) bytes: back to byte-minimal geometry NCH=16 / LOOKBACK=128
//      (R5 measured FETCH=118 MB == input exactly; warmup re-reads fully
//      LLC-absorbed; R9's 64-chunk geometry paid +40 MB HBM).
//      OUT0=200, OUTN=120 -> nb=25/15 batches, both odd, %8==0: clean
//      ping-pong, no remainder epilogue.
//  (b) ceiling: drop the nontemporal hint -- the one structural constant
//      of every ~2.7 TB/s round. nt bypasses L2 write-combining/LLC;
//      output (123 MB) fits the 256 MB LLC. Stores now inline asm
//      (global_store_dwordx4, no nt) so the vmcnt FIFO count is exact.
//  (c) race fix: R9's steady WAITV(16) did not provably cover the consumed
//      load batch (stores ahead of it in FIFO retired first; worked only
//      because load latency < store-ack latency). Recounted: warmup/prologue
//      vmcnt(8), steady vmcnt(16) = {next loads 8 + this-phase-minus-1
//      stores 8} younger than the consumed batch. Over-waiting is safe.
// asm loads kept from R9 (un-sinkable, MLP 8, VGPR 56).

#define ALPHA 0.9f
#define OMA   0.1f
#define EPS_  1e-12f

// aligned(8): row base float-index is (b*2000+t)*962 == 2t mod 4, so odd
// rows give only 8 B alignment for the per-thread quad.
typedef float vf4 __attribute__((ext_vector_type(4), aligned(8)));
typedef float vf2 __attribute__((ext_vector_type(2), aligned(8)));

constexpr int B_ = 16, T_ = 2000, F_ = 481;
constexpr int NCH = 16, LOOKBACK = 128;
constexpr int OUT0 = 200, OUTN = 120;   // 200 + 15*120 = 2000; both %8 == 0
constexpr int ROWF = 2 * F_;            // 962 floats per row (3848 B)

#define SB() __builtin_amdgcn_sched_barrier(0)
// Counted wait: N youngest vmem ops may remain outstanding. sched_barrier
// right after so dependent VALU can't be hoisted past it (rule #18).
#define WAITV(N) do { \
  asm volatile("s_waitcnt vmcnt(" #N ")" ::: "memory"); SB(); \
} while (0)

// Two rows from one pointer: offset imm is 13-bit signed, row stride
// 3848 B fits once. "=&v" earlyclobber: dest must not alias the addr pair.
#define ALD2(d0, d1, p) \
  asm volatile("global_load_dwordx4 %0, %2, off\n\t" \
               "global_load_dwordx4 %1, %2, off offset:3848" \
               : "=&v"(d0), "=&v"(d1) : "v"(p))

// 8-row batch: 8 loads issued back-to-back (MLP 8), pointers advance 8 rows.
#define ALD8(V) do { \
  ALD2(V##0, V##1, p0); ALD2(V##2, V##3, p1); \
  ALD2(V##4, V##5, p2); ALD2(V##6, V##7, p3); \
  p0 += 8 * ROWF; p1 += 8 * ROWF; p2 += 8 * ROWF; p3 += 8 * ROWF; \
} while (0)

#define EMA1(v) do { \
  float aA = __builtin_amdgcn_sqrtf((v).x * (v).x + (v).y * (v).y); \
  float aB = __builtin_amdgcn_sqrtf((v).z * (v).z + (v).w * (v).w); \
  sA = ALPHA * sA + OMA * aA; \
  sB = ALPHA * sB + OMA * aB; \
} while (0)

#define EMA8(V) do { EMA1(V##0); EMA1(V##1); EMA1(V##2); EMA1(V##3); \
                     EMA1(V##4); EMA1(V##5); EMA1(V##6); EMA1(V##7); } while (0)

// One output row: EMA update, rsqrt, one cached (non-nt) 16 B store per lane
// via asm (exact FIFO accounting; dwordx4 needs only 4 B align in HW).
// tid==240 stores only its valid 8 B A-half (16 B would clobber next row's
// f=0, owned by tid 0 of this block).
#define OUT1(v) do { \
  EMA1(v); \
  float iA = __builtin_amdgcn_rsqf(sA + EPS_); \
  float iB = __builtin_amdgcn_rsqf(sB + EPS_); \
  if (hasB) { \
    vf4 o = { (v).x * iA, (v).y * iA, (v).z * iB, (v).w * iB }; \
    asm volatile("global_store_dwordx4 %0, %1, off" :: "v"(op), "v"(o)); \
  } else { \
    vf2 o = { (v).x * iA, (v).y * iA }; \
    asm volatile("global_store_dwordx2 %0, %1, off" :: "v"(op), "v"(o)); \
  } \
  op += ROWF; \
} while (0)

#define OUT8(V) do { OUT1(V##0); OUT1(V##1); OUT1(V##2); OUT1(V##3); \
                     OUT1(V##4); OUT1(V##5); OUT1(V##6); OUT1(V##7); } while (0)

__global__ __launch_bounds__(256, 1)
void specnorm_kernel(const float* __restrict__ x, float* __restrict__ out,
                     float* __restrict__ ws) {
    const int tid = threadIdx.x;
    if (tid > 240) return;              // 241..255 idle (6% waste)
    const int chunk = blockIdx.x;
    const int b = blockIdx.y;
    const bool hasB = (tid < 240);      // tid==240 owns only f=480

    // s0[f] = 0.001 + f*step
    const float step = (float)((0.0001 - 0.001) / (double)(F_ - 1));
    float sA = 0.001f + (float)(2 * tid) * step;
    float sB = 0.001f + (float)(2 * tid + 1) * step;

    const int tout0 = (chunk == 0) ? 0 : OUT0 + (chunk - 1) * OUTN;
    const int nb    = (chunk == 0) ? (OUT0 / 8) : (OUTN / 8);  // 25 or 15
    const int nwarm = (chunk == 0) ? 0 : LOOKBACK;
    const int tstart = tout0 - nwarm;   // >= 72 for chunk >= 1 (OUT0>=LOOKBACK)

    // NOTE: tid==240's 16 B load reads 8 B past the row (= next row's f=0,
    // harmless). At the very last row of the buffer this over-reads 8 B past
    // the end; allocation is page-granular with ~2 KB slack (123,136,000 B
    // is not page-multiple), so the access stays mapped.
    const float* base = x + (size_t)(b * T_ + tstart) * ROWF + 4 * tid;
    const float* p0 = base;
    const float* p1 = base + 2 * ROWF;
    const float* p2 = base + 4 * ROWF;
    const float* p3 = base + 6 * ROWF;
    float* op = out + (size_t)(b * T_ + tout0) * ROWF + 4 * tid;
    (void)ws;

    vf4 a0, a1, a2, a3, a4, a5, a6, a7;
    vf4 b0, b1, b2, b3, b4, b5, b6, b7;

    // ---- warmup: EMA only, no stores. 128 rows = 16 batches w0..w15. ----
    // FIFO is pure loads here: each WAITV(8) retires exactly the batch
    // consumed next. Final ALD8(a) prefetches main batch m0 -- no drain at
    // the warmup->main boundary.
    if (nwarm) {
        ALD8(a);                            // w0
        for (int i = 0; i < 7; ++i) {
            ALD8(b); WAITV(8); EMA8(a);     // issue w(2i+1), consume w(2i)
            ALD8(a); WAITV(8); EMA8(b);     // issue w(2i+2), consume w(2i+1)
        }
        ALD8(b); WAITV(8); EMA8(a);         // issue w15, consume w14
        ALD8(a); WAITV(8); EMA8(b);         // issue m0!,  consume w15
    } else {
        ALD8(a);                            // m0
    }

    // ---- main: nb odd (25 or 15) batches, no remainder. FIFO walk:
    // prologue: [L(m0)] -> ALD8 -> [L(m0),L(m1)]; W8 covers m0.
    // steady:  [S(k-1),L(k+1)] -> ALD8 -> [S(k-1),L(k+1),S?,L(k+2)];
    //          W16 = {S(k),L(k+2)} younger than L(k+1) => covers m(k+1),
    //          drains only the 2-phase-old stores. Never vmcnt(0) in-loop.
    ALD8(b); WAITV(8); OUT8(a);             // issue m1, out m0
    const int pairs = (nb - 3) / 2;         // 11 or 6
    for (int i = 0; i < pairs; ++i) {
        ALD8(a); WAITV(16); OUT8(b);
        ALD8(b); WAITV(16); OUT8(a);
    }
    ALD8(a); WAITV(16); OUT8(b);            // issue m(nb-1), out m(nb-2)
    WAITV(8); OUT8(a);                      // out m(nb-1); endpgm drains rest
}

extern "C" void kernel_launch(void* const* d_in, const int* in_sizes, int n_in,
                              void* d_out, int out_size, void* d_ws, size_t ws_size,
                              hipStream_t stream) {
    const float* x = (const float*)d_in[0];
    float* out = (float*)d_out;
    float* ws = (float*)d_ws;

    dim3 grid(NCH, B_);          // 256 blocks x 4 waves = 1024 waves
    dim3 block(256);
    specnorm_kernel<<<grid, block, 0, stream>>>(x, out, ws);
}